// Round 5
// baseline (283.902 us; speedup 1.0000x reference)
//
#include <hip/hip_runtime.h>

#define BM 128
#define BN 128
#define NSPLIT 8
#define TEMP 0.07f

typedef __attribute__((ext_vector_type(4))) float f32x4;

// L2-normalize rows of X (fp32, N x 512), emit fp8 e4m3 (1 B/elem). One wave/row.
// Also zeroes the completion counter for kmain's last-block finalize.
__global__ __launch_bounds__(256) void knorm(const float* __restrict__ X,
                                             unsigned char* __restrict__ Fq,
                                             int* __restrict__ done, int D) {
  if (blockIdx.x == 0 && threadIdx.x == 0) *done = 0;
  int row = blockIdx.x * 4 + (threadIdx.x >> 6);
  int lane = threadIdx.x & 63;
  const float4* xr = (const float4*)(X + (size_t)row * D);
  float4 a = xr[lane * 2];
  float4 b = xr[lane * 2 + 1];
  float ss = a.x*a.x + a.y*a.y + a.z*a.z + a.w*a.w
           + b.x*b.x + b.y*b.y + b.z*b.z + b.w*b.w;
  #pragma unroll
  for (int off = 1; off < 64; off <<= 1) ss += __shfl_xor(ss, off, 64);
  float r = rsqrtf(ss);
  int lo = 0, hi = 0;
  lo = __builtin_amdgcn_cvt_pk_fp8_f32(a.x*r, a.y*r, lo, false);
  lo = __builtin_amdgcn_cvt_pk_fp8_f32(a.z*r, a.w*r, lo, true);
  hi = __builtin_amdgcn_cvt_pk_fp8_f32(b.x*r, b.y*r, hi, false);
  hi = __builtin_amdgcn_cvt_pk_fp8_f32(b.z*r, b.w*r, hi, true);
  int2 o = make_int2(lo, hi);
  *(int2*)(Fq + (size_t)row * D + lane * 8) = o;
}

// Fused sim-tile GEMM + exp/mask row accumulation, fp8 e4m3.
// 512 threads = 8 waves x 16 rows (BM=128); A resident: af[16]=32 VGPR/wave.
// B staged via 64KB LDS (full K=512), 16B slots XOR-swizzled by row (R4-verified
// conflict-optimal). __launch_bounds__(512,4): 128-reg budget -> 16 waves/CU
// (R4 lesson: 180 VGPR + 76 AGPR > 256 total collapsed occupancy to 1 wave/SIMD).
// Ends with fence->ticket->last-block finalize (removes kfinal + memset nodes).
__global__ __launch_bounds__(512, 4)
void kmain(const unsigned char* __restrict__ F, const int* __restrict__ tgt,
           float* __restrict__ psum, float* __restrict__ pmask,
           int* __restrict__ done, float* __restrict__ out, int N) {
  __shared__ __align__(16) unsigned char Bs[BN * 512];   // 128 rows x 512 B = 64 KB
  __shared__ int h[128];
  __shared__ float wsum[8];
  __shared__ int lastFlag;

  const int tid  = threadIdx.x;
  const int lane = tid & 63;
  const int wave = tid >> 6;       // 0..7
  const int quad = lane >> 4;
  const int l15  = lane & 15;

  const int rowblk   = blockIdx.x / NSPLIT;
  const int split    = blockIdx.x % NSPLIT;   // aligns with XCD round-robin -> L2 reuse
  const int rowbase  = rowblk * BM;
  const int colbase0 = split * (N / NSPLIT);

  // ---- A fragments, loaded once: 16 ksteps x 8 fp8 (16 rows per wave) ----
  long af[16];
  {
    const unsigned char* rp = F + (size_t)(rowbase + wave*16 + l15) * 512 + quad*8;
    #pragma unroll
    for (int k = 0; k < 16; ++k)
      af[k] = *(const long*)(rp + k * 32);
  }

  int trow[4];
  #pragma unroll
  for (int r = 0; r < 4; ++r)
    trow[r] = tgt[rowbase + wave*16 + quad*4 + r];

  float se[4] = {0.f, 0.f, 0.f, 0.f};
  float ms[4] = {0.f, 0.f, 0.f, 0.f};

  const float C1 = (1.0f / TEMP) * 1.4426950408889634f;  // invT*log2(e)
  const float C0 = -C1;

  const int CT = (N / NSPLIT) / BN;   // 8
  for (int ct = 0; ct < CT; ++ct) {
    const int colbase = colbase0 + ct * BN;

    f32x4 acc[8];
    #pragma unroll
    for (int ni = 0; ni < 8; ++ni) acc[ni] = (f32x4){0.f, 0.f, 0.f, 0.f};

    __syncthreads();
    // stage B tile (128 rows x 512 B). phys 16B-slot p holds logical kslot p^(row&31).
    #pragma unroll
    for (int it = 0; it < 8; ++it) {
      const int L   = it * 512 + tid;   // phys 16B-slot linear index (4096 total)
      const int row = L >> 5;           // 32 slots per row
      const int ks  = (L & 31) ^ (row & 31);
      const unsigned char* g = F + (size_t)(colbase + row) * 512 + ks * 16;
      __builtin_amdgcn_global_load_lds(
          (const __attribute__((address_space(1))) void*)g,
          (__attribute__((address_space(3))) void*)(Bs + L * 16), 16, 0, 0);
    }
    __syncthreads();

    #pragma unroll
    for (int k = 0; k < 16; ++k) {
      #pragma unroll
      for (int ni = 0; ni < 8; ++ni) {
        const int row = ni*16 + l15;
        const int g8  = k*4 + quad;                       // 8-byte group in row
        const int a   = row*512 + (((g8 >> 1) ^ (row & 31)) << 4) + (g8 & 1)*8;
        long b = *(const long*)(Bs + a);
        acc[ni] = __builtin_amdgcn_mfma_f32_16x16x32_fp8_fp8(af[k], b, acc[ni], 0, 0, 0);
      }
    }

    // epilogue: fold the 16x128 tile into per-row partial sums
    int tc[8];
    #pragma unroll
    for (int ni = 0; ni < 8; ++ni) tc[ni] = tgt[colbase + ni*16 + l15];
    #pragma unroll
    for (int ni = 0; ni < 8; ++ni)
      #pragma unroll
      for (int r = 0; r < 4; ++r) {
        float v = acc[ni][r];                 // raw dot in [-1,1]
        se[r] += __builtin_amdgcn_exp2f(fmaf(v, C1, C0));
        if (tc[ni] == trow[r]) ms[r] += v;    // diagonal removed in finalize
      }
  }

  // reduce across the 16 lanes of each quad (cols), write per-row partials
  #pragma unroll
  for (int r = 0; r < 4; ++r) {
    float s = se[r], m = ms[r];
    #pragma unroll
    for (int off = 1; off < 16; off <<= 1) {
      s += __shfl_xor(s, off, 64);
      m += __shfl_xor(m, off, 64);
    }
    if (l15 == 0) {
      int row = rowbase + wave*16 + quad*4 + r;
      psum[(size_t)split * N + row]  = s;
      pmask[(size_t)split * N + row] = m;
    }
  }

  // ---- completion ticket; last block finalizes ----
  __threadfence();
  __syncthreads();
  if (tid == 0) lastFlag = (atomicAdd(done, 1) == (N / BM) * NSPLIT - 1);
  __syncthreads();
  if (!lastFlag) return;
  __threadfence();   // acquire: don't read stale partials

  if (tid < 128) h[tid] = 0;
  __syncthreads();
  for (int i = tid; i < N; i += 512) atomicAdd(&h[tgt[i] & 127], 1);
  __syncthreads();

  const float invT = 1.0f / TEMP;
  float local = 0.f;
  for (int i = tid; i < N; i += 512) {
    float s = 0.f, m = 0.f;
    #pragma unroll
    for (int sp = 0; sp < NSPLIT; ++sp) {
      s += psum[(size_t)sp * N + i];
      m += pmask[(size_t)sp * N + i];
    }
    float cnt = (float)(h[tgt[i] & 127] - 1);
    // LSE_i = invT + log(s);  sum_mask sim = (m - selfdot(~1.0)) * invT
    local += (m - 1.0f) * invT / cnt - (logf(s) + invT);
  }
  #pragma unroll
  for (int off = 1; off < 64; off <<= 1) local += __shfl_xor(local, off, 64);
  if (lane == 0) wsum[wave] = local;
  __syncthreads();
  if (tid == 0) {
    float t = 0.f;
    #pragma unroll
    for (int w = 0; w < 8; ++w) t += wsum[w];
    out[0] = -t / (float)N;
  }
}

extern "C" void kernel_launch(void* const* d_in, const int* in_sizes, int n_in,
                              void* d_out, int out_size, void* d_ws, size_t ws_size,
                              hipStream_t stream) {
  const float* X  = (const float*)d_in[0];
  const int* tgt  = (const int*)d_in[1];
  float* out      = (float*)d_out;
  const int N = in_sizes[1];
  const int D = in_sizes[0] / N;

  char* w = (char*)d_ws;
  unsigned char* Fq = (unsigned char*)w;
  size_t off = (size_t)N * D;                          // fp8: 1 B/elem
  float* psum  = (float*)(w + off); off += (size_t)NSPLIT * N * sizeof(float);
  float* pmask = (float*)(w + off); off += (size_t)NSPLIT * N * sizeof(float);
  int* done    = (int*)(w + off);

  knorm<<<N / 4, 256, 0, stream>>>(X, Fq, done, D);
  kmain<<<(N / BM) * NSPLIT, 512, 0, stream>>>(Fq, tgt, psum, pmask, done, out, N);
}

// Round 6
// 225.942 us; speedup vs baseline: 1.2565x; 1.2565x over previous
//
#include <hip/hip_runtime.h>

#define BM 128
#define BN 128
#define NSPLIT 8
#define TEMP 0.07f

typedef __attribute__((ext_vector_type(4))) float f32x4;

// L2-normalize rows of X (fp32, N x 512), emit fp8 e4m3 (1 B/elem). One wave/row.
// Also zeroes the completion counter for kmain's last-block finalize.
__global__ __launch_bounds__(256) void knorm(const float* __restrict__ X,
                                             unsigned char* __restrict__ Fq,
                                             int* __restrict__ done, int D) {
  if (blockIdx.x == 0 && threadIdx.x == 0) *done = 0;
  int row = blockIdx.x * 4 + (threadIdx.x >> 6);
  int lane = threadIdx.x & 63;
  const float4* xr = (const float4*)(X + (size_t)row * D);
  float4 a = xr[lane * 2];
  float4 b = xr[lane * 2 + 1];
  float ss = a.x*a.x + a.y*a.y + a.z*a.z + a.w*a.w
           + b.x*b.x + b.y*b.y + b.z*b.z + b.w*b.w;
  #pragma unroll
  for (int off = 1; off < 64; off <<= 1) ss += __shfl_xor(ss, off, 64);
  float r = rsqrtf(ss);
  int lo = 0, hi = 0;
  lo = __builtin_amdgcn_cvt_pk_fp8_f32(a.x*r, a.y*r, lo, false);
  lo = __builtin_amdgcn_cvt_pk_fp8_f32(a.z*r, a.w*r, lo, true);
  hi = __builtin_amdgcn_cvt_pk_fp8_f32(b.x*r, b.y*r, hi, false);
  hi = __builtin_amdgcn_cvt_pk_fp8_f32(b.z*r, b.w*r, hi, true);
  int2 o = make_int2(lo, hi);
  *(int2*)(Fq + (size_t)row * D + lane * 8) = o;
}

// Fused sim-tile GEMM + exp/mask row accumulation, fp8 e4m3.
// R4 structure (known-good: 256 thr, 32 rows/wave, af[2][16]=64 VGPR, no spill)
// + ct phase-stagger: co-resident block pairs (rowblk differing by 32) start
//   4 column-tiles apart so one block computes while the other drains its
//   B-stage (R4 ran at the serial pipe sum = lockstep barriers).
// __launch_bounds__(256,1): the ONLY config that avoids allocator spills
// (R3 (2,2)-attr and R5 (512,4) both capped the budget and spilled).
__global__ __launch_bounds__(256, 1)
void kmain(const unsigned char* __restrict__ F, const int* __restrict__ tgt,
           float* __restrict__ psum, float* __restrict__ pmask,
           int* __restrict__ done, float* __restrict__ out, int N) {
  __shared__ __align__(16) unsigned char Bs[BN * 512];   // 128 rows x 512 B = 64 KB
  __shared__ int h[128];
  __shared__ float wsum[4];
  __shared__ int lastFlag;

  const int tid  = threadIdx.x;
  const int lane = tid & 63;
  const int wave = tid >> 6;
  const int quad = lane >> 4;
  const int l15  = lane & 15;

  const int rowblk   = blockIdx.x / NSPLIT;
  const int split    = blockIdx.x % NSPLIT;   // == XCD id -> B tile L2-resident
  const int rowbase  = rowblk * BM;
  const int colbase0 = split * (N / NSPLIT);
  const int phase    = ((rowblk >> 5) & 1) * 4;  // anti-phase for co-resident pair

  // ---- A fragments, loaded once: 2 mi x 16 ksteps x 8 fp8 ----
  long af[2][16];
  #pragma unroll
  for (int mi = 0; mi < 2; ++mi) {
    const unsigned char* rp = F + (size_t)(rowbase + wave*32 + mi*16 + l15) * 512 + quad*8;
    #pragma unroll
    for (int k = 0; k < 16; ++k)
      af[mi][k] = *(const long*)(rp + k * 32);
  }

  int trow[2][4];
  #pragma unroll
  for (int mi = 0; mi < 2; ++mi)
    #pragma unroll
    for (int r = 0; r < 4; ++r)
      trow[mi][r] = tgt[rowbase + wave*32 + mi*16 + quad*4 + r];

  float se[2][4] = {{0.f,0.f,0.f,0.f},{0.f,0.f,0.f,0.f}};
  float ms[2][4] = {{0.f,0.f,0.f,0.f},{0.f,0.f,0.f,0.f}};

  const float C1 = (1.0f / TEMP) * 1.4426950408889634f;  // invT*log2(e)
  const float C0 = -C1;

  const int CT = (N / NSPLIT) / BN;   // 8
  for (int t = 0; t < CT; ++t) {
    const int ct = (t + phase) & 7;
    const int colbase = colbase0 + ct * BN;

    f32x4 acc[2][8];
    #pragma unroll
    for (int mi = 0; mi < 2; ++mi)
      #pragma unroll
      for (int ni = 0; ni < 8; ++ni)
        acc[mi][ni] = (f32x4){0.f, 0.f, 0.f, 0.f};

    __syncthreads();
    // stage B tile (128 rows x 512 B). phys 16B-slot p holds logical kslot p^(row&31).
    #pragma unroll
    for (int it = 0; it < 16; ++it) {
      const int L   = it * 256 + tid;   // phys 16B-slot linear index
      const int row = L >> 5;           // 32 slots per row
      const int ks  = (L & 31) ^ (row & 31);
      const unsigned char* g = F + (size_t)(colbase + row) * 512 + ks * 16;
      __builtin_amdgcn_global_load_lds(
          (const __attribute__((address_space(1))) void*)g,
          (__attribute__((address_space(3))) void*)(Bs + L * 16), 16, 0, 0);
    }
    __syncthreads();

    #pragma unroll 2   // limit load-hoisting temps (R4 arch=180; aim lower)
    for (int k = 0; k < 16; ++k) {
      #pragma unroll
      for (int ni = 0; ni < 8; ++ni) {
        const int row = ni*16 + l15;
        const int g8  = k*4 + quad;                       // 8-byte group in row
        const int a   = row*512 + (((g8 >> 1) ^ (row & 31)) << 4) + (g8 & 1)*8;
        long b = *(const long*)(Bs + a);
        acc[0][ni] = __builtin_amdgcn_mfma_f32_16x16x32_fp8_fp8(af[0][k], b, acc[0][ni], 0, 0, 0);
        acc[1][ni] = __builtin_amdgcn_mfma_f32_16x16x32_fp8_fp8(af[1][k], b, acc[1][ni], 0, 0, 0);
      }
    }

    // epilogue: fold the 32x128 tile into per-row partial sums
    int tc[8];
    #pragma unroll
    for (int ni = 0; ni < 8; ++ni) tc[ni] = tgt[colbase + ni*16 + l15];
    #pragma unroll
    for (int mi = 0; mi < 2; ++mi)
      #pragma unroll
      for (int ni = 0; ni < 8; ++ni)
        #pragma unroll
        for (int r = 0; r < 4; ++r) {
          float v = acc[mi][ni][r];                 // raw dot in [-1,1]
          se[mi][r] += __builtin_amdgcn_exp2f(fmaf(v, C1, C0));
          if (tc[ni] == trow[mi][r]) ms[mi][r] += v;  // diagonal removed in finalize
        }
  }

  // reduce across the 16 lanes of each quad (cols), write per-row partials
  #pragma unroll
  for (int mi = 0; mi < 2; ++mi)
    #pragma unroll
    for (int r = 0; r < 4; ++r) {
      float s = se[mi][r], m = ms[mi][r];
      #pragma unroll
      for (int off = 1; off < 16; off <<= 1) {
        s += __shfl_xor(s, off, 64);
        m += __shfl_xor(m, off, 64);
      }
      if (l15 == 0) {
        int row = rowbase + wave*32 + mi*16 + quad*4 + r;
        psum[(size_t)split * N + row]  = s;
        pmask[(size_t)split * N + row] = m;
      }
    }

  // ---- completion ticket; last block finalizes (saves kfinal+memset nodes) ----
  __threadfence();
  __syncthreads();
  if (tid == 0) lastFlag = (atomicAdd(done, 1) == (N / BM) * NSPLIT - 1);
  __syncthreads();
  if (!lastFlag) return;
  __threadfence();   // acquire: don't read stale partials

  if (tid < 128) h[tid] = 0;
  __syncthreads();
  for (int i = tid; i < N; i += 256) atomicAdd(&h[tgt[i] & 127], 1);
  __syncthreads();

  const float invT = 1.0f / TEMP;
  float local = 0.f;
  for (int i = tid; i < N; i += 256) {
    float s = 0.f, m = 0.f;
    #pragma unroll
    for (int sp = 0; sp < NSPLIT; ++sp) {
      s += psum[(size_t)sp * N + i];
      m += pmask[(size_t)sp * N + i];
    }
    float cnt = (float)(h[tgt[i] & 127] - 1);
    // LSE_i = invT + log(s);  sum_mask sim = (m - selfdot(~1.0)) * invT
    local += (m - 1.0f) * invT / cnt - (logf(s) + invT);
  }
  #pragma unroll
  for (int off = 1; off < 64; off <<= 1) local += __shfl_xor(local, off, 64);
  if (lane == 0) wsum[wave] = local;
  __syncthreads();
  if (tid == 0)
    out[0] = -(wsum[0] + wsum[1] + wsum[2] + wsum[3]) / (float)N;
}

extern "C" void kernel_launch(void* const* d_in, const int* in_sizes, int n_in,
                              void* d_out, int out_size, void* d_ws, size_t ws_size,
                              hipStream_t stream) {
  const float* X  = (const float*)d_in[0];
  const int* tgt  = (const int*)d_in[1];
  float* out      = (float*)d_out;
  const int N = in_sizes[1];
  const int D = in_sizes[0] / N;

  char* w = (char*)d_ws;
  unsigned char* Fq = (unsigned char*)w;
  size_t off = (size_t)N * D;                          // fp8: 1 B/elem
  float* psum  = (float*)(w + off); off += (size_t)NSPLIT * N * sizeof(float);
  float* pmask = (float*)(w + off); off += (size_t)NSPLIT * N * sizeof(float);
  int* done    = (int*)(w + off);

  knorm<<<N / 4, 256, 0, stream>>>(X, Fq, done, D);
  kmain<<<(N / BM) * NSPLIT, 256, 0, stream>>>(Fq, tgt, psum, pmask, done, out, N);
}

// Round 7
// 177.619 us; speedup vs baseline: 1.5984x; 1.2721x over previous
//
#include <hip/hip_runtime.h>

#define BM 128
#define BN 64
#define NSPLIT 8
#define TEMP 0.07f

typedef __attribute__((ext_vector_type(4))) float f32x4;

// L2-normalize rows of X (fp32, N x 512), emit fp8 e4m3 (1 B/elem). One wave/row.
// Also zeroes the completion counter for kmain's last-block finalize.
__global__ __launch_bounds__(256) void knorm(const float* __restrict__ X,
                                             unsigned char* __restrict__ Fq,
                                             int* __restrict__ done, int D) {
  if (blockIdx.x == 0 && threadIdx.x == 0) *done = 0;
  int row = blockIdx.x * 4 + (threadIdx.x >> 6);
  int lane = threadIdx.x & 63;
  const float4* xr = (const float4*)(X + (size_t)row * D);
  float4 a = xr[lane * 2];
  float4 b = xr[lane * 2 + 1];
  float ss = a.x*a.x + a.y*a.y + a.z*a.z + a.w*a.w
           + b.x*b.x + b.y*b.y + b.z*b.z + b.w*b.w;
  #pragma unroll
  for (int off = 1; off < 64; off <<= 1) ss += __shfl_xor(ss, off, 64);
  float r = rsqrtf(ss);
  int lo = 0, hi = 0;
  lo = __builtin_amdgcn_cvt_pk_fp8_f32(a.x*r, a.y*r, lo, false);
  lo = __builtin_amdgcn_cvt_pk_fp8_f32(a.z*r, a.w*r, lo, true);
  hi = __builtin_amdgcn_cvt_pk_fp8_f32(b.x*r, b.y*r, hi, false);
  hi = __builtin_amdgcn_cvt_pk_fp8_f32(b.z*r, b.w*r, hi, true);
  int2 o = make_int2(lo, hi);
  *(int2*)(Fq + (size_t)row * D + lane * 8) = o;
}

// Fused sim-tile GEMM + exp/mask row accumulation, fp8 e4m3.
// A resident in registers (af[2][16], 64 VGPR; k-loop FULLY unrolled — R6
// lesson: partial unroll makes af[] dynamically indexed -> scratch spill).
// B double-buffered in LDS: 2 x (64 rows x 512 B) = 64 KB. Loop shape:
//   sync (drains buf[t] loads) -> issue t+1 loads -> compute t
// so the global->LDS transfer flies during MFMA; the barrier pays only a
// short drain (R4/R6's serial stage->compute paid full latency per tile).
// __launch_bounds__(256,1): only config with no allocator spill (R3/R5 lessons).
__global__ __launch_bounds__(256, 1)
void kmain(const unsigned char* __restrict__ F, const int* __restrict__ tgt,
           float* __restrict__ psum, float* __restrict__ pmask,
           int* __restrict__ done, float* __restrict__ out, int N) {
  __shared__ __align__(16) unsigned char Bs[2][BN * 512];   // 2 x 32 KB
  __shared__ int h[128];
  __shared__ float wsum[4];
  __shared__ int lastFlag;

  const int tid  = threadIdx.x;
  const int lane = tid & 63;
  const int wave = tid >> 6;
  const int quad = lane >> 4;
  const int l15  = lane & 15;

  const int rowblk   = blockIdx.x / NSPLIT;
  const int split    = blockIdx.x % NSPLIT;   // == XCD id -> B tiles L2-resident
  const int rowbase  = rowblk * BM;
  const int colbase0 = split * (N / NSPLIT);

  // ---- A fragments, loaded once: 2 mi x 16 ksteps x 8 fp8 ----
  long af[2][16];
  #pragma unroll
  for (int mi = 0; mi < 2; ++mi) {
    const unsigned char* rp = F + (size_t)(rowbase + wave*32 + mi*16 + l15) * 512 + quad*8;
    #pragma unroll
    for (int k = 0; k < 16; ++k)
      af[mi][k] = *(const long*)(rp + k * 32);
  }

  int trow[2][4];
  #pragma unroll
  for (int mi = 0; mi < 2; ++mi)
    #pragma unroll
    for (int r = 0; r < 4; ++r)
      trow[mi][r] = tgt[rowbase + wave*32 + mi*16 + quad*4 + r];

  float se[2][4] = {{0.f,0.f,0.f,0.f},{0.f,0.f,0.f,0.f}};
  float ms[2][4] = {{0.f,0.f,0.f,0.f},{0.f,0.f,0.f,0.f}};

  const float C1 = (1.0f / TEMP) * 1.4426950408889634f;  // invT*log2(e)
  const float C0 = -C1;

  // stage tile ct into buffer b: 64 rows x 512 B, 16B slots XOR-swizzled by row
  // (phys slot p of row holds logical kslot p^(row&31); conflict-free reads,
  //  verified optimal in R4/R5 counters).
  auto stage = [&](int ct, int b) {
    const int colbase = colbase0 + ct * BN;
    unsigned char* dst = Bs[b];
    #pragma unroll
    for (int it = 0; it < 8; ++it) {
      const int L   = it * 256 + tid;   // phys 16B-slot linear index (2048 total)
      const int row = L >> 5;           // 32 slots per row
      const int ks  = (L & 31) ^ (row & 31);
      const unsigned char* g = F + (size_t)(colbase + row) * 512 + ks * 16;
      __builtin_amdgcn_global_load_lds(
          (const __attribute__((address_space(1))) void*)g,
          (__attribute__((address_space(3))) void*)(dst + L * 16), 16, 0, 0);
    }
  };

  const int CT = (N / NSPLIT) / BN;   // 16
  stage(0, 0);

  for (int t = 0; t < CT; ++t) {
    // barrier: compiler emits s_waitcnt vmcnt(0) first -> drains buf[t&1] loads
    // (issued one iteration ago, in flight during the previous compute phase)
    // and guarantees no wave still reads the buffer t+1 will overwrite.
    __syncthreads();
    if (t + 1 < CT) stage(t + 1, (t + 1) & 1);

    const unsigned char* buf = Bs[t & 1];
    const int colbase = colbase0 + t * BN;

    f32x4 acc[2][4];
    #pragma unroll
    for (int mi = 0; mi < 2; ++mi)
      #pragma unroll
      for (int ni = 0; ni < 4; ++ni)
        acc[mi][ni] = (f32x4){0.f, 0.f, 0.f, 0.f};

    #pragma unroll
    for (int k = 0; k < 16; ++k) {
      #pragma unroll
      for (int ni = 0; ni < 4; ++ni) {
        const int row = ni*16 + l15;
        const int g8  = k*4 + quad;                       // 8-byte group in row
        const int a   = row*512 + (((g8 >> 1) ^ (row & 31)) << 4) + (g8 & 1)*8;
        long b = *(const long*)(buf + a);
        acc[0][ni] = __builtin_amdgcn_mfma_f32_16x16x32_fp8_fp8(af[0][k], b, acc[0][ni], 0, 0, 0);
        acc[1][ni] = __builtin_amdgcn_mfma_f32_16x16x32_fp8_fp8(af[1][k], b, acc[1][ni], 0, 0, 0);
      }
    }

    // epilogue: fold the 32x64 tile into per-row partial sums
    int tc[4];
    #pragma unroll
    for (int ni = 0; ni < 4; ++ni) tc[ni] = tgt[colbase + ni*16 + l15];
    #pragma unroll
    for (int mi = 0; mi < 2; ++mi)
      #pragma unroll
      for (int ni = 0; ni < 4; ++ni)
        #pragma unroll
        for (int r = 0; r < 4; ++r) {
          float v = acc[mi][ni][r];                 // raw dot in [-1,1]
          se[mi][r] += __builtin_amdgcn_exp2f(fmaf(v, C1, C0));
          if (tc[ni] == trow[mi][r]) ms[mi][r] += v;  // diagonal removed in finalize
        }
  }

  // reduce across the 16 lanes of each quad (cols), write per-row partials
  #pragma unroll
  for (int mi = 0; mi < 2; ++mi)
    #pragma unroll
    for (int r = 0; r < 4; ++r) {
      float s = se[mi][r], m = ms[mi][r];
      #pragma unroll
      for (int off = 1; off < 16; off <<= 1) {
        s += __shfl_xor(s, off, 64);
        m += __shfl_xor(m, off, 64);
      }
      if (l15 == 0) {
        int row = rowbase + wave*32 + mi*16 + quad*4 + r;
        psum[(size_t)split * N + row]  = s;
        pmask[(size_t)split * N + row] = m;
      }
    }

  // ---- completion ticket; last block finalizes (saves kfinal+memset nodes;
  //      cross-XCD visibility via threadfence+atomic validated in R5/R6) ----
  __threadfence();
  __syncthreads();
  if (tid == 0) lastFlag = (atomicAdd(done, 1) == (N / BM) * NSPLIT - 1);
  __syncthreads();
  if (!lastFlag) return;
  __threadfence();   // acquire: don't read stale partials

  if (tid < 128) h[tid] = 0;
  __syncthreads();
  for (int i = tid; i < N; i += 256) atomicAdd(&h[tgt[i] & 127], 1);
  __syncthreads();

  const float invT = 1.0f / TEMP;
  float local = 0.f;
  for (int i = tid; i < N; i += 256) {
    float s = 0.f, m = 0.f;
    #pragma unroll
    for (int sp = 0; sp < NSPLIT; ++sp) {
      s += psum[(size_t)sp * N + i];
      m += pmask[(size_t)sp * N + i];
    }
    float cnt = (float)(h[tgt[i] & 127] - 1);
    // LSE_i = invT + log(s);  sum_mask sim = (m - selfdot(~1.0)) * invT
    local += (m - 1.0f) * invT / cnt - (logf(s) + invT);
  }
  #pragma unroll
  for (int off = 1; off < 64; off <<= 1) local += __shfl_xor(local, off, 64);
  if (lane == 0) wsum[wave] = local;
  __syncthreads();
  if (tid == 0)
    out[0] = -(wsum[0] + wsum[1] + wsum[2] + wsum[3]) / (float)N;
}

extern "C" void kernel_launch(void* const* d_in, const int* in_sizes, int n_in,
                              void* d_out, int out_size, void* d_ws, size_t ws_size,
                              hipStream_t stream) {
  const float* X  = (const float*)d_in[0];
  const int* tgt  = (const int*)d_in[1];
  float* out      = (float*)d_out;
  const int N = in_sizes[1];
  const int D = in_sizes[0] / N;

  char* w = (char*)d_ws;
  unsigned char* Fq = (unsigned char*)w;
  size_t off = (size_t)N * D;                          // fp8: 1 B/elem
  float* psum  = (float*)(w + off); off += (size_t)NSPLIT * N * sizeof(float);
  float* pmask = (float*)(w + off); off += (size_t)NSPLIT * N * sizeof(float);
  int* done    = (int*)(w + off);

  knorm<<<N / 4, 256, 0, stream>>>(X, Fq, done, D);
  kmain<<<(N / BM) * NSPLIT, 256, 0, stream>>>(Fq, tgt, psum, pmask, done, out, N);
}